// Round 12
// baseline (1005.175 us; speedup 1.0000x reference)
//
#include <hip/hip_runtime.h>

#define NN 100000
#define NE 1600000
#define BN_EPS 1e-5f
#define BSHIFT 2
#define NBUCK ((NN + 3) >> 2)

typedef _Float16 half1;
typedef _Float16 half4 __attribute__((ext_vector_type(4)));
typedef _Float16 h8 __attribute__((ext_vector_type(8)));
typedef float f4 __attribute__((ext_vector_type(4)));
typedef float f8 __attribute__((ext_vector_type(8)));

static inline int divup(int a, int b) { return (a + b - 1) / b; }

// ---------------- preprocessing ----------------

__global__ void hist_kernel(const int* __restrict__ dst, int* __restrict__ deg, int e) {
    int i = blockIdx.x * blockDim.x + threadIdx.x;
    if (i < e) atomicAdd(&deg[dst[i]], 1);
}

__global__ void blksum_kernel(const int* __restrict__ deg, int* __restrict__ blk, int n) {
    __shared__ int red[256];
    int t = threadIdx.x;
    int base = blockIdx.x * 1024 + t * 4;
    int s = 0;
#pragma unroll
    for (int i = 0; i < 4; ++i) {
        int idx = base + i;
        if (idx < n) s += deg[idx];
    }
    red[t] = s;
    __syncthreads();
    for (int off = 128; off > 0; off >>= 1) {
        if (t < off) red[t] += red[t + off];
        __syncthreads();
    }
    if (t == 0) blk[blockIdx.x] = red[0];
}

__global__ void blkscan_kernel(int* __restrict__ blk, int nb, int* __restrict__ row_ptr, int n) {
    __shared__ int sh[256];
    int t = threadIdx.x;
    int v = (t < nb) ? blk[t] : 0;
    sh[t] = v;
    __syncthreads();
    for (int off = 1; off < 256; off <<= 1) {
        int u = (t >= off) ? sh[t - off] : 0;
        __syncthreads();
        sh[t] += u;
        __syncthreads();
    }
    if (t < nb) blk[t] = (t == 0) ? 0 : sh[t - 1];
    if (t == nb - 1) row_ptr[n] = sh[t];
}

__global__ void emit_kernel(const int* __restrict__ deg, const int* __restrict__ blk,
                            int* __restrict__ row_ptr, int n) {
    __shared__ int red[256];
    int t = threadIdx.x;
    int base = blockIdx.x * 1024 + t * 4;
    int d[4];
    int s = 0;
#pragma unroll
    for (int i = 0; i < 4; ++i) {
        int idx = base + i;
        d[i] = (idx < n) ? deg[idx] : 0;
        s += d[i];
    }
    red[t] = s;
    __syncthreads();
    for (int off = 1; off < 256; off <<= 1) {
        int u = (t >= off) ? red[t - off] : 0;
        __syncthreads();
        red[t] += u;
        __syncthreads();
    }
    int run = blk[blockIdx.x] + ((t == 0) ? 0 : red[t - 1]);
#pragma unroll
    for (int i = 0; i < 4; ++i) {
        int idx = base + i;
        if (idx < n) { row_ptr[idx] = run; run += d[i]; }
    }
}

__global__ void dinv_kernel(const int* __restrict__ deg, float* __restrict__ dinv, int n) {
    int i = blockIdx.x * blockDim.x + threadIdx.x;
    if (i < n) {
        int d = deg[i];
        dinv[i] = (d > 0) ? rsqrtf((float)d) : 0.f;
    }
}

// stage A: bin edges by dst>>2 (25k buckets: open-line set 1.6MB < L2, ~64 hits/counter)
__global__ void binA_kernel(const int* __restrict__ src, const int* __restrict__ dst,
                            const int* __restrict__ row_ptr, int* __restrict__ bcur,
                            int2* __restrict__ tmp, int e) {
    int i = blockIdx.x * blockDim.x + threadIdx.x;
    if (i >= e) return;
    int s = src[i], d = dst[i];
    int b = d >> BSHIFT;
    int pos = row_ptr[b << BSHIFT] + atomicAdd(&bcur[b], 1);
    tmp[pos] = make_int2(s, d);
}

// stage B: bucket-ordered tmp -> exact CSR slot; writes land in ~512B L2-hot windows
__global__ void binB_kernel(const int2* __restrict__ tmp, const int* __restrict__ row_ptr,
                            int* __restrict__ cursor, const float* __restrict__ dinv,
                            int2* __restrict__ cw, int e) {
    int i = blockIdx.x * blockDim.x + threadIdx.x;
    if (i >= e) return;
    int2 sd = tmp[i];
    int pos = row_ptr[sd.y] + atomicAdd(&cursor[sd.y], 1);
    cw[pos] = make_int2(sd.x, __float_as_int(-dinv[sd.x] * dinv[sd.y]));
}

// ---------------- fp16 converts for MFMA ----------------

__global__ void cvtx_kernel(const float4* __restrict__ X, half4* __restrict__ Xh, int tot4) {
    int i = blockIdx.x * blockDim.x + threadIdx.x;
    if (i >= tot4) return;
    float4 v = X[i];
    half4 h;
    h.x = (half1)v.x; h.y = (half1)v.y; h.z = (half1)v.z; h.w = (half1)v.w;
    Xh[i] = h;
}

// Wt[og][kd] = W1[og>>6][kd][og&63], fp16 ; Wt is [512][128]
__global__ void transw_kernel(const float* __restrict__ W, half1* __restrict__ Wt) {
    int i = blockIdx.x * blockDim.x + threadIdx.x;
    if (i >= 512 * 128) return;
    int kd = i >> 9;
    int og = i & 511;
    int k = og >> 6, o = og & 63;
    Wt[(size_t)og * 128 + kd] = (half1)W[((size_t)k * 128 + kd) * 64 + o];
}

// ---------------- W padding ----------------
__global__ void padw_kernel(const float* __restrict__ src, float* __restrict__ dst,
                            int K, int dins, int douts, int dind, int doutd) {
    int i = blockIdx.x * blockDim.x + threadIdx.x;
    int tot = K * dind * doutd;
    if (i >= tot) return;
    int o = i % doutd;
    int r = i / doutd;
    int dd = r % dind;
    int k = r / dind;
    dst[i] = (dd < dins && o < douts) ? src[((size_t)k * dins + dd) * douts + o] : 0.f;
}

// ---------------- Clenshaw prop, h8 (16B) gathers, 8-deep unroll — dim == 64 ----------
__global__ void proph8_kernel(const h8* __restrict__ feat, const h8* __restrict__ sub,
                              const h8* __restrict__ add, h8* __restrict__ outh,
                              f8* __restrict__ outf,
                              const int* __restrict__ row_ptr, const int2* __restrict__ cw,
                              int n, float scale, int has_sub, int bnrelu,
                              const float* __restrict__ bn_g, const float* __restrict__ bn_b,
                              const float* __restrict__ bn_m, const float* __restrict__ bn_v) {
    int idx = blockIdx.x * blockDim.x + threadIdx.x;
    if (idx >= n * 8) return;
    int nd = idx >> 3;
    int f = idx & 7;
    int e0 = row_ptr[nd], e1 = row_ptr[nd + 1];
    f8 a0 = {0.f, 0.f, 0.f, 0.f, 0.f, 0.f, 0.f, 0.f}, a1 = a0, a2 = a0, a3 = a0;
    int e = e0;
    for (; e + 8 <= e1; e += 8) {
        int2 q0 = cw[e], q1 = cw[e + 1], q2 = cw[e + 2], q3 = cw[e + 3];
        int2 q4 = cw[e + 4], q5 = cw[e + 5], q6 = cw[e + 6], q7 = cw[e + 7];
        f8 v0 = __builtin_convertvector(feat[(size_t)q0.x * 8 + f], f8);
        f8 v1 = __builtin_convertvector(feat[(size_t)q1.x * 8 + f], f8);
        f8 v2 = __builtin_convertvector(feat[(size_t)q2.x * 8 + f], f8);
        f8 v3 = __builtin_convertvector(feat[(size_t)q3.x * 8 + f], f8);
        f8 v4 = __builtin_convertvector(feat[(size_t)q4.x * 8 + f], f8);
        f8 v5 = __builtin_convertvector(feat[(size_t)q5.x * 8 + f], f8);
        f8 v6 = __builtin_convertvector(feat[(size_t)q6.x * 8 + f], f8);
        f8 v7 = __builtin_convertvector(feat[(size_t)q7.x * 8 + f], f8);
        a0 += __int_as_float(q0.y) * v0;
        a1 += __int_as_float(q1.y) * v1;
        a2 += __int_as_float(q2.y) * v2;
        a3 += __int_as_float(q3.y) * v3;
        a0 += __int_as_float(q4.y) * v4;
        a1 += __int_as_float(q5.y) * v5;
        a2 += __int_as_float(q6.y) * v6;
        a3 += __int_as_float(q7.y) * v7;
    }
    for (; e + 4 <= e1; e += 4) {
        int2 q0 = cw[e], q1 = cw[e + 1], q2 = cw[e + 2], q3 = cw[e + 3];
        f8 v0 = __builtin_convertvector(feat[(size_t)q0.x * 8 + f], f8);
        f8 v1 = __builtin_convertvector(feat[(size_t)q1.x * 8 + f], f8);
        f8 v2 = __builtin_convertvector(feat[(size_t)q2.x * 8 + f], f8);
        f8 v3 = __builtin_convertvector(feat[(size_t)q3.x * 8 + f], f8);
        a0 += __int_as_float(q0.y) * v0;
        a1 += __int_as_float(q1.y) * v1;
        a2 += __int_as_float(q2.y) * v2;
        a3 += __int_as_float(q3.y) * v3;
    }
    for (; e < e1; ++e) {
        int2 q = cw[e];
        a0 += __int_as_float(q.y) * __builtin_convertvector(feat[(size_t)q.x * 8 + f], f8);
    }
    f8 r = ((a0 + a1) + (a2 + a3)) * scale;
    if (has_sub) r -= __builtin_convertvector(sub[idx], f8);
    r += __builtin_convertvector(add[idx], f8);
    if (bnrelu) {
#pragma unroll
        for (int c = 0; c < 8; ++c) {
            int o = f * 8 + c;
            float sc = bn_g[o] * rsqrtf(bn_v[o] + BN_EPS);
            r[c] = fmaxf(fmaf(r[c] - bn_m[o], sc, bn_b[o]), 0.f);
        }
    }
    if (outf) {
        outf[idx] = r;
    } else {
        outh[idx] = __builtin_convertvector(r, h8);
    }
}

// ---------------- Clenshaw prop, half4 gathers, 8-deep unroll — small dims ----------
__global__ void proph_kernel(const half4* __restrict__ feat, const half4* __restrict__ sub,
                             const half4* __restrict__ add, half4* __restrict__ outh,
                             f4* __restrict__ outf,
                             const int* __restrict__ row_ptr, const int2* __restrict__ cw,
                             int n, int dim4, float scale, int has_sub,
                             int bnrelu, int used,
                             const float* __restrict__ bn_g, const float* __restrict__ bn_b,
                             const float* __restrict__ bn_m, const float* __restrict__ bn_v) {
    int idx = blockIdx.x * blockDim.x + threadIdx.x;
    if (idx >= n * dim4) return;
    int nd = idx / dim4;
    int f = idx - nd * dim4;
    int e0 = row_ptr[nd], e1 = row_ptr[nd + 1];
    f4 a0 = {0.f, 0.f, 0.f, 0.f}, a1 = a0, a2 = a0, a3 = a0;
    int e = e0;
    for (; e + 8 <= e1; e += 8) {
        int2 q0 = cw[e], q1 = cw[e + 1], q2 = cw[e + 2], q3 = cw[e + 3];
        int2 q4 = cw[e + 4], q5 = cw[e + 5], q6 = cw[e + 6], q7 = cw[e + 7];
        f4 v0 = __builtin_convertvector(feat[(size_t)q0.x * dim4 + f], f4);
        f4 v1 = __builtin_convertvector(feat[(size_t)q1.x * dim4 + f], f4);
        f4 v2 = __builtin_convertvector(feat[(size_t)q2.x * dim4 + f], f4);
        f4 v3 = __builtin_convertvector(feat[(size_t)q3.x * dim4 + f], f4);
        f4 v4 = __builtin_convertvector(feat[(size_t)q4.x * dim4 + f], f4);
        f4 v5 = __builtin_convertvector(feat[(size_t)q5.x * dim4 + f], f4);
        f4 v6 = __builtin_convertvector(feat[(size_t)q6.x * dim4 + f], f4);
        f4 v7 = __builtin_convertvector(feat[(size_t)q7.x * dim4 + f], f4);
        a0 += __int_as_float(q0.y) * v0;
        a1 += __int_as_float(q1.y) * v1;
        a2 += __int_as_float(q2.y) * v2;
        a3 += __int_as_float(q3.y) * v3;
        a0 += __int_as_float(q4.y) * v4;
        a1 += __int_as_float(q5.y) * v5;
        a2 += __int_as_float(q6.y) * v6;
        a3 += __int_as_float(q7.y) * v7;
    }
    for (; e + 4 <= e1; e += 4) {
        int2 q0 = cw[e], q1 = cw[e + 1], q2 = cw[e + 2], q3 = cw[e + 3];
        f4 v0 = __builtin_convertvector(feat[(size_t)q0.x * dim4 + f], f4);
        f4 v1 = __builtin_convertvector(feat[(size_t)q1.x * dim4 + f], f4);
        f4 v2 = __builtin_convertvector(feat[(size_t)q2.x * dim4 + f], f4);
        f4 v3 = __builtin_convertvector(feat[(size_t)q3.x * dim4 + f], f4);
        a0 += __int_as_float(q0.y) * v0;
        a1 += __int_as_float(q1.y) * v1;
        a2 += __int_as_float(q2.y) * v2;
        a3 += __int_as_float(q3.y) * v3;
    }
    for (; e < e1; ++e) {
        int2 q = cw[e];
        a0 += __int_as_float(q.y) * __builtin_convertvector(feat[(size_t)q.x * dim4 + f], f4);
    }
    f4 r = ((a0 + a1) + (a2 + a3)) * scale;
    if (has_sub) r -= __builtin_convertvector(sub[idx], f4);
    r += __builtin_convertvector(add[idx], f4);
    if (bnrelu) {
#pragma unroll
        for (int c = 0; c < 4; ++c) {
            int o = f * 4 + c;
            if (o < used) {
                float sc = bn_g[o] * rsqrtf(bn_v[o] + BN_EPS);
                r[c] = fmaxf(fmaf(r[c] - bn_m[o], sc, bn_b[o]), 0.f);
            } else r[c] = 0.f;
        }
    }
    if (outf) {
        outf[idx] = r;
    } else {
        half4 h;
        h.x = (half1)r.x; h.y = (half1)r.y; h.z = (half1)r.z; h.w = (half1)r.w;
        outh[idx] = h;
    }
}

// layer-4 final: fp16 gathers/streams at stride 12 (dim4=3), fp32 out at stride 10
__global__ void propl_kernel(const half4* __restrict__ feat, const half4* __restrict__ sub,
                             const half4* __restrict__ add, float* __restrict__ out,
                             const int* __restrict__ row_ptr, const int2* __restrict__ cw,
                             int n) {
    int idx = blockIdx.x * blockDim.x + threadIdx.x;
    if (idx >= n * 3) return;
    int nd = idx / 3;
    int f = idx - nd * 3;
    int e0 = row_ptr[nd], e1 = row_ptr[nd + 1];
    f4 a0 = {0.f, 0.f, 0.f, 0.f}, a1 = a0, a2 = a0, a3 = a0;
    int e = e0;
    for (; e + 4 <= e1; e += 4) {
        int2 q0 = cw[e], q1 = cw[e + 1], q2 = cw[e + 2], q3 = cw[e + 3];
        a0 += __int_as_float(q0.y) * __builtin_convertvector(feat[(size_t)q0.x * 3 + f], f4);
        a1 += __int_as_float(q1.y) * __builtin_convertvector(feat[(size_t)q1.x * 3 + f], f4);
        a2 += __int_as_float(q2.y) * __builtin_convertvector(feat[(size_t)q2.x * 3 + f], f4);
        a3 += __int_as_float(q3.y) * __builtin_convertvector(feat[(size_t)q3.x * 3 + f], f4);
    }
    for (; e < e1; ++e) {
        int2 q = cw[e];
        a0 += __int_as_float(q.y) * __builtin_convertvector(feat[(size_t)q.x * 3 + f], f4);
    }
    f4 r = (a0 + a1) + (a2 + a3);
    r -= __builtin_convertvector(sub[idx], f4);
    r += __builtin_convertvector(add[idx], f4);
    int o = f * 4;
    float* orow = out + (size_t)nd * 10;
    if (o + 0 < 10) orow[o + 0] = r.x;
    if (o + 1 < 10) orow[o + 1] = r.y;
    if (o + 2 < 10) orow[o + 2] = r.z;
    if (o + 3 < 10) orow[o + 3] = r.w;
}

// ---------------- layer-1 GEMM via MFMA (swapped operands) ----------------
__global__ __launch_bounds__(256) void gemm_mfma_kernel(
        const half1* __restrict__ Xh, const half1* __restrict__ Wt,
        const float* __restrict__ bias, half1* __restrict__ CB, int n) {
    int lane = threadIdx.x & 63;
    int wave = threadIdx.x >> 6;
    int m16 = lane & 15;
    int quad = lane >> 4;
    int ks = blockIdx.y * 4 + wave;
    int ntile = blockIdx.x * 64;

    f4 acc[4][4];
#pragma unroll
    for (int nt = 0; nt < 4; ++nt)
#pragma unroll
        for (int i = 0; i < 4; ++i) acc[nt][i] = (f4){0.f, 0.f, 0.f, 0.f};

#pragma unroll
    for (int kc = 0; kc < 4; ++kc) {
        int koff = kc * 32 + quad * 8;
        h8 a[4];
#pragma unroll
        for (int i = 0; i < 4; ++i)
            a[i] = *(const h8*)(Wt + (size_t)(ks * 64 + i * 16 + m16) * 128 + koff);
        h8 b[4];
#pragma unroll
        for (int nt = 0; nt < 4; ++nt) {
            int node = min(ntile + nt * 16 + m16, n - 1);
            b[nt] = *(const h8*)(Xh + (size_t)node * 128 + koff);
        }
#pragma unroll
        for (int nt = 0; nt < 4; ++nt)
#pragma unroll
            for (int i = 0; i < 4; ++i)
                acc[nt][i] = __builtin_amdgcn_mfma_f32_16x16x32_f16(a[i], b[nt], acc[nt][i], 0, 0, 0);
    }

#pragma unroll
    for (int nt = 0; nt < 4; ++nt) {
        int node = ntile + nt * 16 + m16;
        if (node < n) {
#pragma unroll
            for (int i = 0; i < 4; ++i) {
                int ob = i * 16 + quad * 4;
                f4 v = acc[nt][i];
                if (ks == 0) {
                    const f4 b4 = *(const f4*)(bias + ob);
                    v += b4;
                }
                half4 h;
                h.x = (half1)v[0]; h.y = (half1)v[1]; h.z = (half1)v[2]; h.w = (half1)v[3];
                *(half4*)(CB + ((size_t)ks * n + node) * 64 + ob) = h;
            }
        }
    }
}

// ---------------- small-layer GEMM: block = KK waves, wave k, lane = node -------------
template <int KK, int DIN4, int NACC>
__global__ void gemm_smallw_kernel(const float* __restrict__ X, const float* __restrict__ Wp,
                                   const float* __restrict__ bias, int dout,
                                   half4* __restrict__ CB, int n) {
    int lane = threadIdx.x & 63;
    int k = __builtin_amdgcn_readfirstlane((int)(threadIdx.x >> 6));
    int node0 = blockIdx.x * 64 + lane;
    int node = min(node0, n - 1);
    f4 acc[NACC];
#pragma unroll
    for (int i = 0; i < NACC; ++i) {
        f4 v = {0.f, 0.f, 0.f, 0.f};
        if (k == 0 && bias) {
#pragma unroll
            for (int c = 0; c < 4; ++c) {
                int o = i * 4 + c;
                v[c] = (o < dout) ? bias[o] : 0.f;
            }
        }
        acc[i] = v;
    }
    const f4* Xr = (const f4*)(X + (size_t)node * (DIN4 * 4));
    const f4* Wk = (const f4*)(Wp + (size_t)k * (DIN4 * 4) * (NACC * 4));
    for (int d4 = 0; d4 < DIN4; ++d4) {
        f4 xv = Xr[d4];
#pragma unroll
        for (int j = 0; j < 4; ++j) {
            float xs = xv[j];
#pragma unroll
            for (int i = 0; i < NACC; ++i)
                acc[i] += xs * Wk[(d4 * 4 + j) * NACC + i];
        }
    }
    if (node0 < n) {
        size_t base = ((size_t)k * n + node) * NACC;
#pragma unroll
        for (int i = 0; i < NACC; ++i) {
            half4 h;
            h.x = (half1)acc[i].x; h.y = (half1)acc[i].y;
            h.z = (half1)acc[i].z; h.w = (half1)acc[i].w;
            CB[base + i] = h;
        }
    }
}

// ---------------- host driver ----------------

extern "C" void kernel_launch(void* const* d_in, const int* in_sizes, int n_in,
                              void* d_out, int out_size, void* d_ws, size_t ws_size,
                              hipStream_t stream) {
    const float* x  = (const float*)d_in[0];
    const int*   ei = (const int*)d_in[1];
    const float* Wl[4] = {(const float*)d_in[2], (const float*)d_in[4],
                          (const float*)d_in[6], (const float*)d_in[8]};
    const float* bl[4] = {(const float*)d_in[3], (const float*)d_in[5],
                          (const float*)d_in[7], (const float*)d_in[9]};
    const float* bn[3][4];
    for (int l = 0; l < 3; ++l)
        for (int j = 0; j < 4; ++j)
            bn[l][j] = (const float*)d_in[10 + 4 * l + j];

    char* ws = (char*)d_ws;
    size_t off = 0;
    auto alloc = [&](size_t bytes) -> void* {
        void* p = (void*)(ws + off);
        off = (off + bytes + 255) & ~(size_t)255;
        return p;
    };
    int*   deg     = (int*)alloc(NN * 4);
    int*   row_ptr = (int*)alloc((NN + 1) * 4);
    int*   cursor  = (int*)alloc(NN * 4);
    int*   bcur    = (int*)alloc(NBUCK * 4);
    int*   blks    = (int*)alloc(128 * 4);
    float* dinv    = (float*)alloc(NN * 4);
    int2*  cw      = (int2*)alloc((size_t)NE * 8);
    int2*  tmp     = (int2*)alloc((size_t)NE * 8);
    half1* CB1h    = (half1*)alloc((size_t)8 * NN * 64 * 2);
    half1* CBsh    = (half1*)alloc((size_t)6 * NN * 20 * 2);
    half1* S0      = (half1*)alloc((size_t)NN * 64 * 2);
    half1* S1      = (half1*)alloc((size_t)NN * 64 * 2);
    half1* S2      = (half1*)alloc((size_t)NN * 64 * 2);
    float* H1f     = (float*)alloc((size_t)NN * 64 * 4);
    float* H2f     = (float*)alloc((size_t)NN * 20 * 4);
    float* H3f     = (float*)alloc((size_t)NN * 12 * 4);
    float* Wp2     = (float*)alloc((size_t)6 * 64 * 20 * 4);
    float* Wp3     = (float*)alloc((size_t)4 * 20 * 12 * 4);
    float* Wp4     = (float*)alloc((size_t)4 * 12 * 12 * 4);
    half1* Xh      = (half1*)alloc((size_t)NN * 128 * 2);
    half1* Wt1     = (half1*)alloc((size_t)512 * 128 * 2);

    const int* srcp = ei;
    const int* dstp = ei + NE;
    const int nscan = divup(NN, 1024);
    const int NB = divup(NN, 64);

    hipMemsetAsync(deg, 0, NN * 4, stream);
    hipMemsetAsync(cursor, 0, NN * 4, stream);
    hipMemsetAsync(bcur, 0, NBUCK * 4, stream);
    hist_kernel<<<divup(NE, 256), 256, 0, stream>>>(dstp, deg, NE);
    blksum_kernel<<<nscan, 256, 0, stream>>>(deg, blks, NN);
    blkscan_kernel<<<1, 256, 0, stream>>>(blks, nscan, row_ptr, NN);
    emit_kernel<<<nscan, 256, 0, stream>>>(deg, blks, row_ptr, NN);
    dinv_kernel<<<divup(NN, 256), 256, 0, stream>>>(deg, dinv, NN);
    binA_kernel<<<divup(NE, 256), 256, 0, stream>>>(srcp, dstp, row_ptr, bcur, tmp, NE);
    binB_kernel<<<divup(NE, 256), 256, 0, stream>>>(tmp, row_ptr, cursor, dinv, cw, NE);

    cvtx_kernel<<<divup(NN * 32, 256), 256, 0, stream>>>((const float4*)x, (half4*)Xh, NN * 32);
    transw_kernel<<<divup(512 * 128, 256), 256, 0, stream>>>(Wl[0], Wt1);
    padw_kernel<<<divup(6 * 64 * 20, 256), 256, 0, stream>>>(Wl[1], Wp2, 6, 64, 18, 64, 20);
    padw_kernel<<<divup(4 * 20 * 12, 256), 256, 0, stream>>>(Wl[2], Wp3, 4, 18, 9, 20, 12);
    padw_kernel<<<divup(4 * 12 * 12, 256), 256, 0, stream>>>(Wl[3], Wp4, 4, 9, 10, 12, 12);

    // dim-64 prop (h8 gathers)
    auto prop1 = [&](const half1* feat, const half1* sub, const half1* add,
                     half1* outh, float* outf, float scale, int bnrelu,
                     const float* g, const float* bb, const float* m, const float* v) {
        proph8_kernel<<<divup(NN * 8, 256), 256, 0, stream>>>(
            (const h8*)feat, (const h8*)sub, (const h8*)add,
            (h8*)outh, (f8*)outf, row_ptr, cw, NN, scale,
            sub != nullptr, bnrelu, g, bb, m, v);
    };
    // small-dim prop (half4 gathers)
    auto prop = [&](const half1* feat, const half1* sub, const half1* add,
                    half1* outh, float* outf, int dim4, float scale,
                    int bnrelu, int used, const float* g, const float* bb,
                    const float* m, const float* v) {
        proph_kernel<<<divup(NN * dim4, 256), 256, 0, stream>>>(
            (const half4*)feat, (const half4*)sub, (const half4*)add,
            (half4*)outh, (f4*)outf, row_ptr, cw, NN, dim4, scale,
            sub != nullptr, bnrelu, used, g, bb, m, v);
    };

    // ---- layer 1 (din=128, dout=64, K=8) -> H1f ----
    gemm_mfma_kernel<<<dim3(NB, 2), 256, 0, stream>>>(Xh, Wt1, bl[0], CB1h, NN);
    {
        auto C = [&](int k) { return (const half1*)(CB1h + (size_t)k * NN * 64); };
        prop1(C(7), nullptr, C(6), S0, nullptr, 2.f, 0, 0, 0, 0, 0);
        prop1(S0, C(7), C(5), S1, nullptr, 2.f, 0, 0, 0, 0, 0);
        prop1(S1, S0, C(4), S2, nullptr, 2.f, 0, 0, 0, 0, 0);
        prop1(S2, S1, C(3), S0, nullptr, 2.f, 0, 0, 0, 0, 0);
        prop1(S0, S2, C(2), S1, nullptr, 2.f, 0, 0, 0, 0, 0);
        prop1(S1, S0, C(1), S2, nullptr, 2.f, 0, 0, 0, 0, 0);
        prop1(S2, S1, C(0), nullptr, H1f, 1.f, 1,
              bn[0][0], bn[0][1], bn[0][2], bn[0][3]);
    }

    // ---- layer 2 (din=64, dout=18 pad 20, K=6): X=H1f -> H2f ----
    gemm_smallw_kernel<6, 16, 5><<<NB, 384, 0, stream>>>(H1f, Wp2, bl[1], 18,
                                                         (half4*)CBsh, NN);
    {
        auto C = [&](int k) { return (const half1*)(CBsh + (size_t)k * NN * 20); };
        prop(C(5), nullptr, C(4), S0, nullptr, 5, 2.f, 0, 18, 0, 0, 0, 0);
        prop(S0, C(5), C(3), S1, nullptr, 5, 2.f, 0, 18, 0, 0, 0, 0);
        prop(S1, S0, C(2), S2, nullptr, 5, 2.f, 0, 18, 0, 0, 0, 0);
        prop(S2, S1, C(1), S0, nullptr, 5, 2.f, 0, 18, 0, 0, 0, 0);
        prop(S0, S2, C(0), nullptr, H2f, 5, 1.f, 1, 18,
             bn[1][0], bn[1][1], bn[1][2], bn[1][3]);
    }

    // ---- layer 3 (din=18 str20, dout=9 pad 12, K=4): X=H2f -> H3f ----
    gemm_smallw_kernel<4, 5, 3><<<NB, 256, 0, stream>>>(H2f, Wp3, bl[2], 9,
                                                        (half4*)CBsh, NN);
    {
        auto C = [&](int k) { return (const half1*)(CBsh + (size_t)k * NN * 12); };
        prop(C(3), nullptr, C(2), S0, nullptr, 3, 2.f, 0, 9, 0, 0, 0, 0);
        prop(S0, C(3), C(1), S1, nullptr, 3, 2.f, 0, 9, 0, 0, 0, 0);
        prop(S1, S0, C(0), nullptr, H3f, 3, 1.f, 1, 9,
             bn[2][0], bn[2][1], bn[2][2], bn[2][3]);
    }

    // ---- layer 4 (din=9 str12, dout=10 pad 12, K=4): X=H3f -> d_out ----
    gemm_smallw_kernel<4, 3, 3><<<NB, 256, 0, stream>>>(H3f, Wp4, bl[3], 10,
                                                        (half4*)CBsh, NN);
    {
        auto C = [&](int k) { return (const half1*)(CBsh + (size_t)k * NN * 12); };
        prop(C(3), nullptr, C(2), S0, nullptr, 3, 2.f, 0, 10, 0, 0, 0, 0);
        prop(S0, C(3), C(1), S1, nullptr, 3, 2.f, 0, 10, 0, 0, 0, 0);
        propl_kernel<<<divup(NN * 3, 256), 256, 0, stream>>>(
            (const half4*)S1, (const half4*)S0, (const half4*)CBsh,
            (float*)d_out, row_ptr, cw, NN);
    }
}

// Round 13
// 884.977 us; speedup vs baseline: 1.1358x; 1.1358x over previous
//
#include <hip/hip_runtime.h>

#define NN 100000
#define NE 1600000
#define BN_EPS 1e-5f

typedef _Float16 half1;
typedef _Float16 half4 __attribute__((ext_vector_type(4)));
typedef _Float16 h8 __attribute__((ext_vector_type(8)));
typedef float f4 __attribute__((ext_vector_type(4)));
typedef float f8 __attribute__((ext_vector_type(8)));

static inline int divup(int a, int b) { return (a + b - 1) / b; }

// ---------------- preprocessing ----------------

__global__ void hist_kernel(const int* __restrict__ dst, int* __restrict__ deg, int e) {
    int i = blockIdx.x * blockDim.x + threadIdx.x;
    if (i < e) atomicAdd(&deg[dst[i]], 1);
}

__global__ void blksum_kernel(const int* __restrict__ deg, int* __restrict__ blk, int n) {
    __shared__ int red[256];
    int t = threadIdx.x;
    int base = blockIdx.x * 1024 + t * 4;
    int s = 0;
#pragma unroll
    for (int i = 0; i < 4; ++i) {
        int idx = base + i;
        if (idx < n) s += deg[idx];
    }
    red[t] = s;
    __syncthreads();
    for (int off = 128; off > 0; off >>= 1) {
        if (t < off) red[t] += red[t + off];
        __syncthreads();
    }
    if (t == 0) blk[blockIdx.x] = red[0];
}

__global__ void blkscan_kernel(int* __restrict__ blk, int nb, int* __restrict__ row_ptr, int n) {
    __shared__ int sh[256];
    int t = threadIdx.x;
    int v = (t < nb) ? blk[t] : 0;
    sh[t] = v;
    __syncthreads();
    for (int off = 1; off < 256; off <<= 1) {
        int u = (t >= off) ? sh[t - off] : 0;
        __syncthreads();
        sh[t] += u;
        __syncthreads();
    }
    if (t < nb) blk[t] = (t == 0) ? 0 : sh[t - 1];
    if (t == nb - 1) row_ptr[n] = sh[t];
}

__global__ void emit_kernel(const int* __restrict__ deg, const int* __restrict__ blk,
                            int* __restrict__ row_ptr, int n) {
    __shared__ int red[256];
    int t = threadIdx.x;
    int base = blockIdx.x * 1024 + t * 4;
    int d[4];
    int s = 0;
#pragma unroll
    for (int i = 0; i < 4; ++i) {
        int idx = base + i;
        d[i] = (idx < n) ? deg[idx] : 0;
        s += d[i];
    }
    red[t] = s;
    __syncthreads();
    for (int off = 1; off < 256; off <<= 1) {
        int u = (t >= off) ? red[t - off] : 0;
        __syncthreads();
        red[t] += u;
        __syncthreads();
    }
    int run = blk[blockIdx.x] + ((t == 0) ? 0 : red[t - 1]);
#pragma unroll
    for (int i = 0; i < 4; ++i) {
        int idx = base + i;
        if (idx < n) { row_ptr[idx] = run; run += d[i]; }
    }
}

__global__ void dinv_kernel(const int* __restrict__ deg, float* __restrict__ dinv, int n) {
    int i = blockIdx.x * blockDim.x + threadIdx.x;
    if (i < n) {
        int d = deg[i];
        dinv[i] = (d > 0) ? rsqrtf((float)d) : 0.f;
    }
}

// single-stage scatter (100k counters: low atomic contention). Non-temporal store:
// the CSR lines are written once and not re-read before eviction — skip L2 allocation.
__global__ void scatter_kernel(const int* __restrict__ src, const int* __restrict__ dst,
                               const int* __restrict__ row_ptr, int* __restrict__ cursor,
                               const float* __restrict__ dinv,
                               int2* __restrict__ cw, int e) {
    int i = blockIdx.x * blockDim.x + threadIdx.x;
    if (i >= e) return;
    int s = src[i], d = dst[i];
    int pos = row_ptr[d] + atomicAdd(&cursor[d], 1);
    unsigned long long packed =
        (unsigned int)s | ((unsigned long long)(unsigned int)__float_as_int(-dinv[s] * dinv[d]) << 32);
    __builtin_nontemporal_store(packed, (unsigned long long*)&cw[pos]);
}

// ---------------- fp16 converts for MFMA ----------------

__global__ void cvtx_kernel(const float4* __restrict__ X, half4* __restrict__ Xh, int tot4) {
    int i = blockIdx.x * blockDim.x + threadIdx.x;
    if (i >= tot4) return;
    float4 v = X[i];
    half4 h;
    h.x = (half1)v.x; h.y = (half1)v.y; h.z = (half1)v.z; h.w = (half1)v.w;
    Xh[i] = h;
}

// Wt[og][kd] = W1[og>>6][kd][og&63], fp16 ; Wt is [512][128]
__global__ void transw_kernel(const float* __restrict__ W, half1* __restrict__ Wt) {
    int i = blockIdx.x * blockDim.x + threadIdx.x;
    if (i >= 512 * 128) return;
    int kd = i >> 9;
    int og = i & 511;
    int k = og >> 6, o = og & 63;
    Wt[(size_t)og * 128 + kd] = (half1)W[((size_t)k * 128 + kd) * 64 + o];
}

// ---------------- W padding ----------------
__global__ void padw_kernel(const float* __restrict__ src, float* __restrict__ dst,
                            int K, int dins, int douts, int dind, int doutd) {
    int i = blockIdx.x * blockDim.x + threadIdx.x;
    int tot = K * dind * doutd;
    if (i >= tot) return;
    int o = i % doutd;
    int r = i / doutd;
    int dd = r % dind;
    int k = r / dind;
    dst[i] = (dd < dins && o < douts) ? src[((size_t)k * dins + dd) * douts + o] : 0.f;
}

// ---------------- Clenshaw prop, h8 (16B) gathers — dim == 64 ----------------
__global__ void proph8_kernel(const h8* __restrict__ feat, const h8* __restrict__ sub,
                              const h8* __restrict__ add, h8* __restrict__ outh,
                              f8* __restrict__ outf,
                              const int* __restrict__ row_ptr, const int2* __restrict__ cw,
                              int n, float scale, int has_sub, int bnrelu,
                              const float* __restrict__ bn_g, const float* __restrict__ bn_b,
                              const float* __restrict__ bn_m, const float* __restrict__ bn_v) {
    int idx = blockIdx.x * blockDim.x + threadIdx.x;
    if (idx >= n * 8) return;
    int nd = idx >> 3;
    int f = idx & 7;
    int e0 = row_ptr[nd], e1 = row_ptr[nd + 1];
    f8 a0 = {0.f, 0.f, 0.f, 0.f, 0.f, 0.f, 0.f, 0.f}, a1 = a0, a2 = a0, a3 = a0;
    int e = e0;
    for (; e + 4 <= e1; e += 4) {
        int2 q0 = cw[e], q1 = cw[e + 1], q2 = cw[e + 2], q3 = cw[e + 3];
        f8 v0 = __builtin_convertvector(feat[(size_t)q0.x * 8 + f], f8);
        f8 v1 = __builtin_convertvector(feat[(size_t)q1.x * 8 + f], f8);
        f8 v2 = __builtin_convertvector(feat[(size_t)q2.x * 8 + f], f8);
        f8 v3 = __builtin_convertvector(feat[(size_t)q3.x * 8 + f], f8);
        a0 += __int_as_float(q0.y) * v0;
        a1 += __int_as_float(q1.y) * v1;
        a2 += __int_as_float(q2.y) * v2;
        a3 += __int_as_float(q3.y) * v3;
    }
    for (; e < e1; ++e) {
        int2 q = cw[e];
        a0 += __int_as_float(q.y) * __builtin_convertvector(feat[(size_t)q.x * 8 + f], f8);
    }
    f8 r = ((a0 + a1) + (a2 + a3)) * scale;
    if (has_sub) r -= __builtin_convertvector(sub[idx], f8);
    r += __builtin_convertvector(add[idx], f8);
    if (bnrelu) {
#pragma unroll
        for (int c = 0; c < 8; ++c) {
            int o = f * 8 + c;
            float sc = bn_g[o] * rsqrtf(bn_v[o] + BN_EPS);
            r[c] = fmaxf(fmaf(r[c] - bn_m[o], sc, bn_b[o]), 0.f);
        }
    }
    if (outf) {
        outf[idx] = r;
    } else {
        outh[idx] = __builtin_convertvector(r, h8);
    }
}

// ---------------- Clenshaw prop, half4 gathers — small dims ----------------
__global__ void proph_kernel(const half4* __restrict__ feat, const half4* __restrict__ sub,
                             const half4* __restrict__ add, half4* __restrict__ outh,
                             f4* __restrict__ outf,
                             const int* __restrict__ row_ptr, const int2* __restrict__ cw,
                             int n, int dim4, float scale, int has_sub,
                             int bnrelu, int used,
                             const float* __restrict__ bn_g, const float* __restrict__ bn_b,
                             const float* __restrict__ bn_m, const float* __restrict__ bn_v) {
    int idx = blockIdx.x * blockDim.x + threadIdx.x;
    if (idx >= n * dim4) return;
    int nd = idx / dim4;
    int f = idx - nd * dim4;
    int e0 = row_ptr[nd], e1 = row_ptr[nd + 1];
    f4 a0 = {0.f, 0.f, 0.f, 0.f}, a1 = a0, a2 = a0, a3 = a0;
    int e = e0;
    for (; e + 4 <= e1; e += 4) {
        int2 q0 = cw[e], q1 = cw[e + 1], q2 = cw[e + 2], q3 = cw[e + 3];
        f4 v0 = __builtin_convertvector(feat[(size_t)q0.x * dim4 + f], f4);
        f4 v1 = __builtin_convertvector(feat[(size_t)q1.x * dim4 + f], f4);
        f4 v2 = __builtin_convertvector(feat[(size_t)q2.x * dim4 + f], f4);
        f4 v3 = __builtin_convertvector(feat[(size_t)q3.x * dim4 + f], f4);
        a0 += __int_as_float(q0.y) * v0;
        a1 += __int_as_float(q1.y) * v1;
        a2 += __int_as_float(q2.y) * v2;
        a3 += __int_as_float(q3.y) * v3;
    }
    for (; e < e1; ++e) {
        int2 q = cw[e];
        a0 += __int_as_float(q.y) * __builtin_convertvector(feat[(size_t)q.x * dim4 + f], f4);
    }
    f4 r = ((a0 + a1) + (a2 + a3)) * scale;
    if (has_sub) r -= __builtin_convertvector(sub[idx], f4);
    r += __builtin_convertvector(add[idx], f4);
    if (bnrelu) {
#pragma unroll
        for (int c = 0; c < 4; ++c) {
            int o = f * 4 + c;
            if (o < used) {
                float sc = bn_g[o] * rsqrtf(bn_v[o] + BN_EPS);
                r[c] = fmaxf(fmaf(r[c] - bn_m[o], sc, bn_b[o]), 0.f);
            } else r[c] = 0.f;
        }
    }
    if (outf) {
        outf[idx] = r;
    } else {
        half4 h;
        h.x = (half1)r.x; h.y = (half1)r.y; h.z = (half1)r.z; h.w = (half1)r.w;
        outh[idx] = h;
    }
}

// layer-4 final: fp16 gathers/streams at stride 12 (dim4=3), fp32 out at stride 10
__global__ void propl_kernel(const half4* __restrict__ feat, const half4* __restrict__ sub,
                             const half4* __restrict__ add, float* __restrict__ out,
                             const int* __restrict__ row_ptr, const int2* __restrict__ cw,
                             int n) {
    int idx = blockIdx.x * blockDim.x + threadIdx.x;
    if (idx >= n * 3) return;
    int nd = idx / 3;
    int f = idx - nd * 3;
    int e0 = row_ptr[nd], e1 = row_ptr[nd + 1];
    f4 a0 = {0.f, 0.f, 0.f, 0.f}, a1 = a0, a2 = a0, a3 = a0;
    int e = e0;
    for (; e + 4 <= e1; e += 4) {
        int2 q0 = cw[e], q1 = cw[e + 1], q2 = cw[e + 2], q3 = cw[e + 3];
        a0 += __int_as_float(q0.y) * __builtin_convertvector(feat[(size_t)q0.x * 3 + f], f4);
        a1 += __int_as_float(q1.y) * __builtin_convertvector(feat[(size_t)q1.x * 3 + f], f4);
        a2 += __int_as_float(q2.y) * __builtin_convertvector(feat[(size_t)q2.x * 3 + f], f4);
        a3 += __int_as_float(q3.y) * __builtin_convertvector(feat[(size_t)q3.x * 3 + f], f4);
    }
    for (; e < e1; ++e) {
        int2 q = cw[e];
        a0 += __int_as_float(q.y) * __builtin_convertvector(feat[(size_t)q.x * 3 + f], f4);
    }
    f4 r = (a0 + a1) + (a2 + a3);
    r -= __builtin_convertvector(sub[idx], f4);
    r += __builtin_convertvector(add[idx], f4);
    int o = f * 4;
    float* orow = out + (size_t)nd * 10;
    if (o + 0 < 10) orow[o + 0] = r.x;
    if (o + 1 < 10) orow[o + 1] = r.y;
    if (o + 2 < 10) orow[o + 2] = r.z;
    if (o + 3 < 10) orow[o + 3] = r.w;
}

// ---------------- layer-1 GEMM via MFMA (swapped operands) ----------------
__global__ __launch_bounds__(256) void gemm_mfma_kernel(
        const half1* __restrict__ Xh, const half1* __restrict__ Wt,
        const float* __restrict__ bias, half1* __restrict__ CB, int n) {
    int lane = threadIdx.x & 63;
    int wave = threadIdx.x >> 6;
    int m16 = lane & 15;
    int quad = lane >> 4;
    int ks = blockIdx.y * 4 + wave;
    int ntile = blockIdx.x * 64;

    f4 acc[4][4];
#pragma unroll
    for (int nt = 0; nt < 4; ++nt)
#pragma unroll
        for (int i = 0; i < 4; ++i) acc[nt][i] = (f4){0.f, 0.f, 0.f, 0.f};

#pragma unroll
    for (int kc = 0; kc < 4; ++kc) {
        int koff = kc * 32 + quad * 8;
        h8 a[4];
#pragma unroll
        for (int i = 0; i < 4; ++i)
            a[i] = *(const h8*)(Wt + (size_t)(ks * 64 + i * 16 + m16) * 128 + koff);
        h8 b[4];
#pragma unroll
        for (int nt = 0; nt < 4; ++nt) {
            int node = min(ntile + nt * 16 + m16, n - 1);
            b[nt] = *(const h8*)(Xh + (size_t)node * 128 + koff);
        }
#pragma unroll
        for (int nt = 0; nt < 4; ++nt)
#pragma unroll
            for (int i = 0; i < 4; ++i)
                acc[nt][i] = __builtin_amdgcn_mfma_f32_16x16x32_f16(a[i], b[nt], acc[nt][i], 0, 0, 0);
    }

#pragma unroll
    for (int nt = 0; nt < 4; ++nt) {
        int node = ntile + nt * 16 + m16;
        if (node < n) {
#pragma unroll
            for (int i = 0; i < 4; ++i) {
                int ob = i * 16 + quad * 4;
                f4 v = acc[nt][i];
                if (ks == 0) {
                    const f4 b4 = *(const f4*)(bias + ob);
                    v += b4;
                }
                half4 h;
                h.x = (half1)v[0]; h.y = (half1)v[1]; h.z = (half1)v[2]; h.w = (half1)v[3];
                *(half4*)(CB + ((size_t)ks * n + node) * 64 + ob) = h;
            }
        }
    }
}

// ---------------- small-layer GEMM: block = KK waves, wave k, lane = node -------------
template <int KK, int DIN4, int NACC>
__global__ void gemm_smallw_kernel(const float* __restrict__ X, const float* __restrict__ Wp,
                                   const float* __restrict__ bias, int dout,
                                   half4* __restrict__ CB, int n) {
    int lane = threadIdx.x & 63;
    int k = __builtin_amdgcn_readfirstlane((int)(threadIdx.x >> 6));
    int node0 = blockIdx.x * 64 + lane;
    int node = min(node0, n - 1);
    f4 acc[NACC];
#pragma unroll
    for (int i = 0; i < NACC; ++i) {
        f4 v = {0.f, 0.f, 0.f, 0.f};
        if (k == 0 && bias) {
#pragma unroll
            for (int c = 0; c < 4; ++c) {
                int o = i * 4 + c;
                v[c] = (o < dout) ? bias[o] : 0.f;
            }
        }
        acc[i] = v;
    }
    const f4* Xr = (const f4*)(X + (size_t)node * (DIN4 * 4));
    const f4* Wk = (const f4*)(Wp + (size_t)k * (DIN4 * 4) * (NACC * 4));
    for (int d4 = 0; d4 < DIN4; ++d4) {
        f4 xv = Xr[d4];
#pragma unroll
        for (int j = 0; j < 4; ++j) {
            float xs = xv[j];
#pragma unroll
            for (int i = 0; i < NACC; ++i)
                acc[i] += xs * Wk[(d4 * 4 + j) * NACC + i];
        }
    }
    if (node0 < n) {
        size_t base = ((size_t)k * n + node) * NACC;
#pragma unroll
        for (int i = 0; i < NACC; ++i) {
            half4 h;
            h.x = (half1)acc[i].x; h.y = (half1)acc[i].y;
            h.z = (half1)acc[i].z; h.w = (half1)acc[i].w;
            CB[base + i] = h;
        }
    }
}

// ---------------- host driver ----------------

extern "C" void kernel_launch(void* const* d_in, const int* in_sizes, int n_in,
                              void* d_out, int out_size, void* d_ws, size_t ws_size,
                              hipStream_t stream) {
    const float* x  = (const float*)d_in[0];
    const int*   ei = (const int*)d_in[1];
    const float* Wl[4] = {(const float*)d_in[2], (const float*)d_in[4],
                          (const float*)d_in[6], (const float*)d_in[8]};
    const float* bl[4] = {(const float*)d_in[3], (const float*)d_in[5],
                          (const float*)d_in[7], (const float*)d_in[9]};
    const float* bn[3][4];
    for (int l = 0; l < 3; ++l)
        for (int j = 0; j < 4; ++j)
            bn[l][j] = (const float*)d_in[10 + 4 * l + j];

    char* ws = (char*)d_ws;
    size_t off = 0;
    auto alloc = [&](size_t bytes) -> void* {
        void* p = (void*)(ws + off);
        off = (off + bytes + 255) & ~(size_t)255;
        return p;
    };
    int*   deg     = (int*)alloc(NN * 4);
    int*   row_ptr = (int*)alloc((NN + 1) * 4);
    int*   cursor  = (int*)alloc(NN * 4);
    int*   blks    = (int*)alloc(128 * 4);
    float* dinv    = (float*)alloc(NN * 4);
    int2*  cw      = (int2*)alloc((size_t)NE * 8);
    half1* CB1h    = (half1*)alloc((size_t)8 * NN * 64 * 2);
    half1* CBsh    = (half1*)alloc((size_t)6 * NN * 20 * 2);
    half1* S0      = (half1*)alloc((size_t)NN * 64 * 2);
    half1* S1      = (half1*)alloc((size_t)NN * 64 * 2);
    half1* S2      = (half1*)alloc((size_t)NN * 64 * 2);
    float* H1f     = (float*)alloc((size_t)NN * 64 * 4);
    float* H2f     = (float*)alloc((size_t)NN * 20 * 4);
    float* H3f     = (float*)alloc((size_t)NN * 12 * 4);
    float* Wp2     = (float*)alloc((size_t)6 * 64 * 20 * 4);
    float* Wp3     = (float*)alloc((size_t)4 * 20 * 12 * 4);
    float* Wp4     = (float*)alloc((size_t)4 * 12 * 12 * 4);
    half1* Xh      = (half1*)alloc((size_t)NN * 128 * 2);
    half1* Wt1     = (half1*)alloc((size_t)512 * 128 * 2);

    const int* srcp = ei;
    const int* dstp = ei + NE;
    const int nscan = divup(NN, 1024);
    const int NB = divup(NN, 64);

    hipMemsetAsync(deg, 0, NN * 4, stream);
    hipMemsetAsync(cursor, 0, NN * 4, stream);
    hist_kernel<<<divup(NE, 256), 256, 0, stream>>>(dstp, deg, NE);
    blksum_kernel<<<nscan, 256, 0, stream>>>(deg, blks, NN);
    blkscan_kernel<<<1, 256, 0, stream>>>(blks, nscan, row_ptr, NN);
    emit_kernel<<<nscan, 256, 0, stream>>>(deg, blks, row_ptr, NN);
    dinv_kernel<<<divup(NN, 256), 256, 0, stream>>>(deg, dinv, NN);
    scatter_kernel<<<divup(NE, 256), 256, 0, stream>>>(srcp, dstp, row_ptr, cursor, dinv, cw, NE);

    cvtx_kernel<<<divup(NN * 32, 256), 256, 0, stream>>>((const float4*)x, (half4*)Xh, NN * 32);
    transw_kernel<<<divup(512 * 128, 256), 256, 0, stream>>>(Wl[0], Wt1);
    padw_kernel<<<divup(6 * 64 * 20, 256), 256, 0, stream>>>(Wl[1], Wp2, 6, 64, 18, 64, 20);
    padw_kernel<<<divup(4 * 20 * 12, 256), 256, 0, stream>>>(Wl[2], Wp3, 4, 18, 9, 20, 12);
    padw_kernel<<<divup(4 * 12 * 12, 256), 256, 0, stream>>>(Wl[3], Wp4, 4, 9, 10, 12, 12);

    // dim-64 prop (h8 gathers)
    auto prop1 = [&](const half1* feat, const half1* sub, const half1* add,
                     half1* outh, float* outf, float scale, int bnrelu,
                     const float* g, const float* bb, const float* m, const float* v) {
        proph8_kernel<<<divup(NN * 8, 256), 256, 0, stream>>>(
            (const h8*)feat, (const h8*)sub, (const h8*)add,
            (h8*)outh, (f8*)outf, row_ptr, cw, NN, scale,
            sub != nullptr, bnrelu, g, bb, m, v);
    };
    // small-dim prop (half4 gathers)
    auto prop = [&](const half1* feat, const half1* sub, const half1* add,
                    half1* outh, float* outf, int dim4, float scale,
                    int bnrelu, int used, const float* g, const float* bb,
                    const float* m, const float* v) {
        proph_kernel<<<divup(NN * dim4, 256), 256, 0, stream>>>(
            (const half4*)feat, (const half4*)sub, (const half4*)add,
            (half4*)outh, (f4*)outf, row_ptr, cw, NN, dim4, scale,
            sub != nullptr, bnrelu, used, g, bb, m, v);
    };

    // ---- layer 1 (din=128, dout=64, K=8) -> H1f ----
    gemm_mfma_kernel<<<dim3(NB, 2), 256, 0, stream>>>(Xh, Wt1, bl[0], CB1h, NN);
    {
        auto C = [&](int k) { return (const half1*)(CB1h + (size_t)k * NN * 64); };
        prop1(C(7), nullptr, C(6), S0, nullptr, 2.f, 0, 0, 0, 0, 0);
        prop1(S0, C(7), C(5), S1, nullptr, 2.f, 0, 0, 0, 0, 0);
        prop1(S1, S0, C(4), S2, nullptr, 2.f, 0, 0, 0, 0, 0);
        prop1(S2, S1, C(3), S0, nullptr, 2.f, 0, 0, 0, 0, 0);
        prop1(S0, S2, C(2), S1, nullptr, 2.f, 0, 0, 0, 0, 0);
        prop1(S1, S0, C(1), S2, nullptr, 2.f, 0, 0, 0, 0, 0);
        prop1(S2, S1, C(0), nullptr, H1f, 1.f, 1,
              bn[0][0], bn[0][1], bn[0][2], bn[0][3]);
    }

    // ---- layer 2 (din=64, dout=18 pad 20, K=6): X=H1f -> H2f ----
    gemm_smallw_kernel<6, 16, 5><<<NB, 384, 0, stream>>>(H1f, Wp2, bl[1], 18,
                                                         (half4*)CBsh, NN);
    {
        auto C = [&](int k) { return (const half1*)(CBsh + (size_t)k * NN * 20); };
        prop(C(5), nullptr, C(4), S0, nullptr, 5, 2.f, 0, 18, 0, 0, 0, 0);
        prop(S0, C(5), C(3), S1, nullptr, 5, 2.f, 0, 18, 0, 0, 0, 0);
        prop(S1, S0, C(2), S2, nullptr, 5, 2.f, 0, 18, 0, 0, 0, 0);
        prop(S2, S1, C(1), S0, nullptr, 5, 2.f, 0, 18, 0, 0, 0, 0);
        prop(S0, S2, C(0), nullptr, H2f, 5, 1.f, 1, 18,
             bn[1][0], bn[1][1], bn[1][2], bn[1][3]);
    }

    // ---- layer 3 (din=18 str20, dout=9 pad 12, K=4): X=H2f -> H3f ----
    gemm_smallw_kernel<4, 5, 3><<<NB, 256, 0, stream>>>(H2f, Wp3, bl[2], 9,
                                                        (half4*)CBsh, NN);
    {
        auto C = [&](int k) { return (const half1*)(CBsh + (size_t)k * NN * 12); };
        prop(C(3), nullptr, C(2), S0, nullptr, 3, 2.f, 0, 9, 0, 0, 0, 0);
        prop(S0, C(3), C(1), S1, nullptr, 3, 2.f, 0, 9, 0, 0, 0, 0);
        prop(S1, S0, C(0), nullptr, H3f, 3, 1.f, 1, 9,
             bn[2][0], bn[2][1], bn[2][2], bn[2][3]);
    }

    // ---- layer 4 (din=9 str12, dout=10 pad 12, K=4): X=H3f -> d_out ----
    gemm_smallw_kernel<4, 3, 3><<<NB, 256, 0, stream>>>(H3f, Wp4, bl[3], 10,
                                                        (half4*)CBsh, NN);
    {
        auto C = [&](int k) { return (const half1*)(CBsh + (size_t)k * NN * 12); };
        prop(C(3), nullptr, C(2), S0, nullptr, 3, 2.f, 0, 10, 0, 0, 0, 0);
        prop(S0, C(3), C(1), S1, nullptr, 3, 2.f, 0, 10, 0, 0, 0, 0);
        propl_kernel<<<divup(NN * 3, 256), 256, 0, stream>>>(
            (const half4*)S1, (const half4*)S0, (const half4*)CBsh,
            (float*)d_out, row_ptr, cw, NN);
    }
}